// Round 3
// baseline (619.606 us; speedup 1.0000x reference)
//
#include <hip/hip_runtime.h>
#include <math.h>

#define B_SZ 8
#define Hh 64
#define Ww 64
#define L 4096
#define Dm 96
#define Din 192
#define Kd 4
#define Ns 16
#define CPROJ 38
#define ROWW 40           // padded permuted row: [B16|C16|dt6|pad2]
#define NCHUNK 64
#define CHUNK 64

__device__ __forceinline__ float siluf_(float x){ return x / (1.f + __expf(-x)); }
__device__ __forceinline__ float softplusf_(float x){ return (x > 20.f) ? x : __logf(1.f + __expf(x)); }

// ---------------- prep: transpose weights ----------------
__global__ void prep_kernel(const float* __restrict__ inw,    // (384,96)
                            const float* __restrict__ xpw,    // (4,38,192)
                            const float* __restrict__ outw,   // (96,192)
                            float* __restrict__ wt_in,        // (96,384)
                            float* __restrict__ wt_x,         // (192,152)
                            float* __restrict__ wt_out){      // (192,96)
  int i = blockIdx.x * blockDim.x + threadIdx.x;
  if (i < Dm*2*Din){ int k = i/(2*Din); int o = i%(2*Din); wt_in[i] = inw[o*Dm + k]; }
  int j = i - Dm*2*Din;
  if (j >= 0 && j < Din*Kd*CPROJ){ int k = j/(Kd*CPROJ); int c = j%(Kd*CPROJ); wt_x[j] = xpw[c*Din + k]; }
  int l = j - Din*Kd*CPROJ;
  if (l >= 0 && l < Din*Dm){ int dd = l/Dm; int o = l%Dm; wt_out[l] = outw[o*Din + dd]; }
}

// ---------------- generic tiled GEMM: C(128p x 128o tile) = X(p,K) @ W(K,O) ----------------
// 256 threads = 16 pg x 16 og; per-thread 8p x 8o; LDS X-tile XOR-swizzled; W streamed via L2.
// EPI 0: inproj split -> xpart | silu(z).  EPI 1: xdbl permuted scatter (image-tiled p-blocks).
// EPI 2: plain store to out.
template<int KDIM, int OREAL, int EPI>
__global__ __launch_bounds__(256) void gemm_kernel(const float* __restrict__ X,
    const float* __restrict__ W, float* __restrict__ out0, float* __restrict__ out1){
  __shared__ float4 xt[128*24];    // 48 KB
  const int tid = threadIdx.x;
  const int pg = tid & 15, og = tid >> 4;
  const int pblk = blockIdx.x & 255;
  const int oblk = blockIdx.x >> 8;
  const int p0 = pblk * 128;
  int oc = oblk*128 + og*8;
  if (oc > OREAL-8) oc = OREAL-8;
  const int sw = pg & 7;

  float acc[8][8];
  #pragma unroll
  for (int i=0;i<8;i++){
    #pragma unroll
    for (int j2=0;j2<8;j2++) acc[i][j2] = 0.f;
  }

  for (int kp = 0; kp < KDIM/96; ++kp){
    __syncthreads();
    for (int idx = tid; idx < 128*24; idx += 256){
      int pp = idx/24, k4 = idx%24;
      size_t prow;
      if (EPI == 1){
        int b = pblk >> 5, tau = pblk & 31;
        int h = ((tau>>2)<<3) + (pp>>4);
        int w = ((tau&3)<<4) + (pp&15);
        prow = (size_t)b*L + h*64 + w;
      } else prow = (size_t)p0 + pp;
      float4 v = *(const float4*)&X[prow*KDIM + (size_t)kp*96 + k4*4];
      xt[pp*24 + (k4 ^ (pp&7))] = v;
    }
    __syncthreads();

    for (int k4 = 0; k4 < 24; ++k4){
      float4 wv[8];
      #pragma unroll
      for (int kk=0;kk<4;kk++){
        const float* wr = &W[(size_t)(kp*96 + k4*4 + kk)*OREAL + oc];
        wv[kk*2]   = *(const float4*)wr;
        wv[kk*2+1] = *(const float4*)(wr+4);
      }
      float4 xv[8];
      #pragma unroll
      for (int i=0;i<8;i++) xv[i] = xt[(pg+16*i)*24 + (k4 ^ sw)];
      #pragma unroll
      for (int kk=0;kk<4;kk++){
        const float4 wa = wv[kk*2], wb = wv[kk*2+1];
        #pragma unroll
        for (int i=0;i<8;i++){
          const float xk = ((const float*)&xv[i])[kk];
          acc[i][0] += xk*wa.x; acc[i][1] += xk*wa.y; acc[i][2] += xk*wa.z; acc[i][3] += xk*wa.w;
          acc[i][4] += xk*wb.x; acc[i][5] += xk*wb.y; acc[i][6] += xk*wb.z; acc[i][7] += xk*wb.w;
        }
      }
    }
  }

  if (EPI == 0){
    #pragma unroll
    for (int i=0;i<8;i++){
      size_t p = (size_t)p0 + pg + 16*i;
      if (oc < Din){
        float4 v0 = make_float4(acc[i][0],acc[i][1],acc[i][2],acc[i][3]);
        float4 v1 = make_float4(acc[i][4],acc[i][5],acc[i][6],acc[i][7]);
        *(float4*)&out0[p*Din + oc] = v0;
        *(float4*)&out0[p*Din + oc + 4] = v1;
      } else {
        int zo = oc - Din;
        float4 v0 = make_float4(siluf_(acc[i][0]),siluf_(acc[i][1]),siluf_(acc[i][2]),siluf_(acc[i][3]));
        float4 v1 = make_float4(siluf_(acc[i][4]),siluf_(acc[i][5]),siluf_(acc[i][6]),siluf_(acc[i][7]));
        *(float4*)&out1[p*Din + zo] = v0;
        *(float4*)&out1[p*Din + zo + 4] = v1;
      }
    }
  } else if (EPI == 1){
    const int b = pblk >> 5, tau = pblk & 31;
    #pragma unroll
    for (int i=0;i<8;i++){
      int q = pg + 16*i;
      int h = ((tau>>2)<<3) + (q>>4);
      int w = ((tau&3)<<4) + (q&15);
      int hw = h*64 + w;
      int t1 = ((hw&63)<<6) | (hw>>6);
      #pragma unroll
      for (int j2=0;j2<8;j2++){
        int c = oc + j2;
        int kd = c / CPROJ; int cc = c - kd*CPROJ;
        int t = (kd==0)? hw : (kd==1)? t1 : (kd==2)? (L-1-hw) : (L-1-t1);
        int dcol = (cc < 6) ? (32+cc) : (cc-6);
        out0[((size_t)(b*Kd+kd)*L + t)*ROWW + dcol] = acc[i][j2];
      }
    }
  } else {
    #pragma unroll
    for (int i=0;i<8;i++){
      size_t p = (size_t)p0 + pg + 16*i;
      *(float4*)&out0[p*Dm + oc]     = make_float4(acc[i][0],acc[i][1],acc[i][2],acc[i][3]);
      *(float4*)&out0[p*Dm + oc + 4] = make_float4(acc[i][4],acc[i][5],acc[i][6],acc[i][7]);
    }
  }
}

// ---------------- depthwise 3x3 conv + bias + silu ----------------
__global__ __launch_bounds__(256) void conv_kernel(const float* __restrict__ xp,
    const float* __restrict__ cw, const float* __restrict__ cb, float* __restrict__ u){
  const int gid = blockIdx.x * 256 + threadIdx.x;
  const int d = gid % Din; const int p = gid / Din;
  const int b = p / L; const int hw = p % L; const int h = hw >> 6; const int w = hw & 63;
  float acc = cb[d];
  #pragma unroll
  for (int i=-1;i<=1;i++){
    const int hh = h + i; if (hh < 0 || hh >= Hh) continue;
    #pragma unroll
    for (int j=-1;j<=1;j++){
      const int ww = w + j; if (ww < 0 || ww >= Ww) continue;
      acc += xp[((size_t)(b*L + hh*Ww + ww))*Din + d] * cw[d*9 + (i+1)*3 + (j+1)];
    }
  }
  u[(size_t)p*Din + d] = siluf_(acc);
}

// u position of direction k's timestep t
__device__ __forceinline__ int pos_of(int k, int t){
  if (k == 0) return t;
  if (k == 1) return ((t & 63) << 6) | (t >> 6);
  if (k == 2) return L-1-t;
  const int tp = L-1-t; return ((tp & 63) << 6) | (tp >> 6);
}

// power ladder: e[n] = e1^(n+1), tree-shaped
__device__ __forceinline__ void ladder_(float e1, float* e){
  e[0]=e1;
  #pragma unroll
  for (int n=1;n<16;n++){ int P=n+1; e[n] = e[(P+1)/2 - 1] * e[P/2 - 1]; }
}

// ---------------- scan pass 1: per-chunk local scan -> q (zero-init end state), S (sum delta) ----------------
__global__ __launch_bounds__(192) void scanq_kernel(const float* __restrict__ u,
    const float* __restrict__ xq, const float* __restrict__ dtw,
    const float* __restrict__ dtb, const float* __restrict__ alog,
    float* __restrict__ qout, float* __restrict__ Sout){
  const int bid = blockIdx.x;
  const int c = bid & 63; const int k = (bid >> 6) & 3; const int b = bid >> 8;
  const int d = threadIdx.x;
  const int bk = b*Kd + k;
  float wdt[6];
  #pragma unroll
  for (int r=0;r<6;r++) wdt[r] = dtw[(k*Din + d)*6 + r];
  const float bias = dtb[k*Din + d];
  float a2[16]; bool fast = true;
  #pragma unroll
  for (int n=0;n<16;n++){
    a2[n] = -__expf(alog[(k*Din + d)*16 + n]);
    fast = fast && (fabsf(a2[n] + (float)(n+1)) < 1e-5f*(float)(n+1));
  }
  float hst[16];
  #pragma unroll
  for (int n=0;n<16;n++) hst[n] = 0.f;
  float S = 0.f;
  const int t0 = c * CHUNK;
  for (int t = t0; t < t0 + CHUNK; ++t){
    const float* __restrict__ row = xq + ((size_t)bk*L + t)*ROWW;
    float dr = bias;
    #pragma unroll
    for (int r=0;r<6;r++) dr += row[32+r]*wdt[r];
    const float delta = softplusf_(dr);
    S += delta;
    const float uval = u[((size_t)b*L + pos_of(k,t))*Din + d];
    const float du = delta * uval;
    float e[16];
    if (fast) ladder_(__expf(-delta), e);
    else {
      #pragma unroll
      for (int n=0;n<16;n++) e[n] = __expf(delta * a2[n]);
    }
    #pragma unroll
    for (int n=0;n<16;n++) hst[n] = e[n]*hst[n] + du*row[n];
  }
  const size_t base = ((size_t)bk*NCHUNK + c)*Ns*Din + d;
  #pragma unroll
  for (int n=0;n<16;n++) qout[base + (size_t)n*Din] = hst[n];
  Sout[((size_t)bk*NCHUNK + c)*Din + d] = S;
}

// ---------------- combine: sequential over chunks, h_in written in-place over q ----------------
__global__ __launch_bounds__(256) void combine_kernel(const float* __restrict__ alog,
    float* __restrict__ q, const float* __restrict__ Sin){
  const int gid = blockIdx.x * 256 + threadIdx.x;
  if (gid >= B_SZ*Kd*Ns*Din) return;
  const int d = gid % Din; const int n = (gid / Din) % Ns; const int bk = gid / (Din*Ns);
  const int k = bk & 3;
  const float A = -__expf(alog[(k*Din + d)*16 + n]);
  float h = 0.f;
  for (int c=0;c<NCHUNK;c++){
    const size_t idx = (((size_t)bk*NCHUNK + c)*Ns + n)*Din + d;
    const float qv = q[idx];
    q[idx] = h;
    h = __expf(A * Sin[((size_t)bk*NCHUNK + c)*Din + d]) * h + qv;
  }
}

// ---------------- scan pass 2: paired directions (k, k+2), LDS y-window, coalesced store ----------------
__global__ __launch_bounds__(192) void scany_kernel(const float* __restrict__ u,
    const float* __restrict__ xq, const float* __restrict__ dtw,
    const float* __restrict__ dtb, const float* __restrict__ alog,
    const float* __restrict__ Dsin, const float* __restrict__ hin,
    float* __restrict__ bufA, float* __restrict__ bufB){
  __shared__ float ywin[64][Din];
  const int bid = blockIdx.x;
  const int c = bid & 63; const int pair = (bid >> 6) & 1; const int b = bid >> 7;
  const int d = threadIdx.x;
  const int kA = pair, kB = pair + 2;
  const int bkA = b*Kd + kA, bkB = b*Kd + kB;

  float wdtA[6], wdtB[6];
  #pragma unroll
  for (int r=0;r<6;r++){ wdtA[r] = dtw[(kA*Din + d)*6 + r]; wdtB[r] = dtw[(kB*Din + d)*6 + r]; }
  const float biasA = dtb[kA*Din + d], biasB = dtb[kB*Din + d];
  const float DvA = Dsin[kA*Din + d], DvB = Dsin[kB*Din + d];
  float a2A[16], a2B[16]; bool fastA = true, fastB = true;
  #pragma unroll
  for (int n=0;n<16;n++){
    a2A[n] = -__expf(alog[(kA*Din + d)*16 + n]);
    a2B[n] = -__expf(alog[(kB*Din + d)*16 + n]);
    fastA = fastA && (fabsf(a2A[n] + (float)(n+1)) < 1e-5f*(float)(n+1));
    fastB = fastB && (fabsf(a2B[n] + (float)(n+1)) < 1e-5f*(float)(n+1));
  }
  float hA[16], hB[16];
  {
    const size_t baA = ((size_t)bkA*NCHUNK + c)*Ns*Din + d;
    const size_t baB = ((size_t)bkB*NCHUNK + (63-c))*Ns*Din + d;
    #pragma unroll
    for (int n=0;n<16;n++){ hA[n] = hin[baA + (size_t)n*Din]; hB[n] = hin[baB + (size_t)n*Din]; }
  }
  const int tA0 = c*CHUNK, tB0 = (63-c)*CHUNK;

  for (int s=0;s<64;s++){
    // ---- chain A, time tA0+s, window row s
    {
      const float* __restrict__ row = xq + ((size_t)bkA*L + tA0 + s)*ROWW;
      float dr = biasA;
      #pragma unroll
      for (int r=0;r<6;r++) dr += row[32+r]*wdtA[r];
      const float delta = softplusf_(dr);
      const int gp = pair ? (s*64 + c) : (c*64 + s);
      const float uval = u[((size_t)b*L + gp)*Din + d];
      const float du = delta * uval;
      float e[16];
      if (fastA) ladder_(__expf(-delta), e);
      else {
        #pragma unroll
        for (int n=0;n<16;n++) e[n] = __expf(delta * a2A[n]);
      }
      float y0=0.f,y1=0.f,y2=0.f,y3=0.f;
      #pragma unroll
      for (int n=0;n<16;n+=4){
        hA[n]   = e[n]*hA[n]     + du*row[n];
        hA[n+1] = e[n+1]*hA[n+1] + du*row[n+1];
        hA[n+2] = e[n+2]*hA[n+2] + du*row[n+2];
        hA[n+3] = e[n+3]*hA[n+3] + du*row[n+3];
        y0 += hA[n]*row[16+n]; y1 += hA[n+1]*row[17+n];
        y2 += hA[n+2]*row[18+n]; y3 += hA[n+3]*row[19+n];
      }
      const float y = (y0+y1)+(y2+y3) + DvA*uval;
      if (s < 32) ywin[s][d] = y; else ywin[s][d] += y;
    }
    // ---- chain B, time tB0+s, window row 63-s
    {
      const float* __restrict__ row = xq + ((size_t)bkB*L + tB0 + s)*ROWW;
      float dr = biasB;
      #pragma unroll
      for (int r=0;r<6;r++) dr += row[32+r]*wdtB[r];
      const float delta = softplusf_(dr);
      const int rr = 63 - s;
      const int gp = pair ? (rr*64 + c) : (c*64 + rr);
      const float uval = u[((size_t)b*L + gp)*Din + d];
      const float du = delta * uval;
      float e[16];
      if (fastB) ladder_(__expf(-delta), e);
      else {
        #pragma unroll
        for (int n=0;n<16;n++) e[n] = __expf(delta * a2B[n]);
      }
      float y0=0.f,y1=0.f,y2=0.f,y3=0.f;
      #pragma unroll
      for (int n=0;n<16;n+=4){
        hB[n]   = e[n]*hB[n]     + du*row[n];
        hB[n+1] = e[n+1]*hB[n+1] + du*row[n+1];
        hB[n+2] = e[n+2]*hB[n+2] + du*row[n+2];
        hB[n+3] = e[n+3]*hB[n+3] + du*row[n+3];
        y0 += hB[n]*row[16+n]; y1 += hB[n+1]*row[17+n];
        y2 += hB[n+2]*row[18+n]; y3 += hB[n+3]*row[19+n];
      }
      const float y = (y0+y1)+(y2+y3) + DvB*uval;
      if (s < 32) ywin[rr][d] = y; else ywin[rr][d] += y;
    }
  }
  __syncthreads();
  float* __restrict__ dst = pair ? bufB : bufA;
  for (int g = threadIdx.x; g < 64*48; g += 192){
    const int r = g/48, qq = g%48;
    const int gp = pair ? (r*64 + c) : (c*64 + r);
    *(float4*)&dst[((size_t)b*L + gp)*Din + qq*4] = *(const float4*)&ywin[r][qq*4];
  }
}

// ---------------- merge(A+B) + LN + gate ----------------
__global__ __launch_bounds__(192) void lnz_kernel(const float* __restrict__ ya,
    const float* __restrict__ yb, const float* __restrict__ z,
    const float* __restrict__ gw, const float* __restrict__ gb,
    float* __restrict__ yg){
  __shared__ float red[2][4];
  const int p = blockIdx.x;
  const int d = threadIdx.x;
  const float yv = ya[(size_t)p*Din + d] + yb[(size_t)p*Din + d];
  float s = yv, ss = yv*yv;
  #pragma unroll
  for (int off=32; off>=1; off>>=1){ s += __shfl_down(s, off); ss += __shfl_down(ss, off); }
  const int wave = d >> 6;
  if ((d & 63) == 0){ red[0][wave] = s; red[1][wave] = ss; }
  __syncthreads();
  const float mu = (red[0][0]+red[0][1]+red[0][2]) * (1.f/Din);
  const float var = (red[1][0]+red[1][1]+red[1][2]) * (1.f/Din) - mu*mu;
  const float inv = rsqrtf(var + 1e-5f);
  yg[(size_t)p*Din + d] = ((yv - mu)*inv*gw[d] + gb[d]) * z[(size_t)p*Din + d];
}

extern "C" void kernel_launch(void* const* d_in, const int* in_sizes, int n_in,
                              void* d_out, int out_size, void* d_ws, size_t ws_size,
                              hipStream_t stream) {
  const float* x      = (const float*)d_in[0];
  const float* inw    = (const float*)d_in[1];
  const float* convw  = (const float*)d_in[2];
  const float* convb  = (const float*)d_in[3];
  const float* xprojw = (const float*)d_in[4];
  const float* dtw    = (const float*)d_in[5];
  const float* dtb    = (const float*)d_in[6];
  const float* alog   = (const float*)d_in[7];
  const float* Ds     = (const float*)d_in[8];
  const float* gw     = (const float*)d_in[9];
  const float* gb     = (const float*)d_in[10];
  const float* outw   = (const float*)d_in[11];
  float* out = (float*)d_out;

  float* ws = (float*)d_ws;
  const size_t nBLD  = (size_t)B_SZ*L*Din;
  const size_t nXQ   = (size_t)B_SZ*Kd*L*ROWW;
  const size_t nQ    = (size_t)B_SZ*Kd*NCHUNK*Ns*Din;
  const size_t nS    = (size_t)B_SZ*Kd*NCHUNK*Din;
  size_t off = 0;
  float* xpart = ws + off; off += nBLD;   // reused as bufA after conv
  float* zbuf  = ws + off; off += nBLD;
  float* ubuf  = ws + off; off += nBLD;
  float* xq    = ws + off; off += nXQ;
  float* qbuf  = ws + off; off += nQ;     // reused as yg after scany
  float* Sbuf  = ws + off; off += nS;
  float* bufB  = ws + off; off += nBLD;
  float* wt_in = ws + off; off += (size_t)Dm*2*Din;
  float* wt_x  = ws + off; off += (size_t)Din*Kd*CPROJ;
  float* wt_out= ws + off; off += (size_t)Din*Dm;

  const int prepN = Dm*2*Din + Din*Kd*CPROJ + Din*Dm;
  prep_kernel<<<(prepN + 255)/256, 256, 0, stream>>>(inw, xprojw, outw, wt_in, wt_x, wt_out);
  gemm_kernel<Dm, 2*Din, 0><<<256*3, 256, 0, stream>>>(x, wt_in, xpart, zbuf);
  conv_kernel<<<(int)(nBLD/256), 256, 0, stream>>>(xpart, convw, convb, ubuf);
  gemm_kernel<Din, Kd*CPROJ, 1><<<256*2, 256, 0, stream>>>(ubuf, wt_x, xq, nullptr);
  scanq_kernel<<<B_SZ*Kd*NCHUNK, Din, 0, stream>>>(ubuf, xq, dtw, dtb, alog, qbuf, Sbuf);
  combine_kernel<<<(B_SZ*Kd*Ns*Din + 255)/256, 256, 0, stream>>>(alog, qbuf, Sbuf);
  scany_kernel<<<B_SZ*2*NCHUNK, Din, 0, stream>>>(ubuf, xq, dtw, dtb, alog, Ds, qbuf, xpart, bufB);
  lnz_kernel<<<B_SZ*L, Din, 0, stream>>>(xpart, bufB, zbuf, gw, gb, qbuf);
  gemm_kernel<Din, Dm, 2><<<256*1, 256, 0, stream>>>(qbuf, wt_out, out, nullptr);
}

// Round 4
// 524.583 us; speedup vs baseline: 1.1811x; 1.1811x over previous
//
#include <hip/hip_runtime.h>
#include <math.h>

#define B_SZ 8
#define Hh 64
#define Ww 64
#define L 4096
#define Dm 96
#define Din 192
#define Kd 4
#define Ns 16
#define CPROJ 38
#define ROWW 40           // padded permuted row: [B16|C16|dt6|pad2]
#define NCHUNK 64
#define CHUNK 64

__device__ __forceinline__ float siluf_(float x){ return x / (1.f + __expf(-x)); }

// ---------------- prep: transpose weights ----------------
__global__ void prep_kernel(const float* __restrict__ inw,    // (384,96)
                            const float* __restrict__ xpw,    // (4,38,192)
                            const float* __restrict__ outw,   // (96,192)
                            float* __restrict__ wt_in,        // (96,384)
                            float* __restrict__ wt_x,         // (192,152)
                            float* __restrict__ wt_out){      // (192,96)
  int i = blockIdx.x * blockDim.x + threadIdx.x;
  if (i < Dm*2*Din){ int k = i/(2*Din); int o = i%(2*Din); wt_in[i] = inw[o*Dm + k]; }
  int j = i - Dm*2*Din;
  if (j >= 0 && j < Din*Kd*CPROJ){ int k = j/(Kd*CPROJ); int c = j%(Kd*CPROJ); wt_x[j] = xpw[c*Din + k]; }
  int l = j - Din*Kd*CPROJ;
  if (l >= 0 && l < Din*Dm){ int dd = l/Dm; int o = l%Dm; wt_out[l] = outw[o*Din + dd]; }
}

// ---------------- generic tiled GEMM: C(128p x 128o tile) = X(p,K) @ W(K,O) ----------------
template<int KDIM, int OREAL, int EPI>
__global__ __launch_bounds__(256) void gemm_kernel(const float* __restrict__ X,
    const float* __restrict__ W, float* __restrict__ out0, float* __restrict__ out1){
  __shared__ float4 xt[128*24];    // 48 KB
  const int tid = threadIdx.x;
  const int pg = tid & 15, og = tid >> 4;
  const int pblk = blockIdx.x & 255;
  const int oblk = blockIdx.x >> 8;
  const int p0 = pblk * 128;
  int oc = oblk*128 + og*8;
  if (oc > OREAL-8) oc = OREAL-8;
  const int sw = pg & 7;

  float acc[8][8];
  #pragma unroll
  for (int i=0;i<8;i++){
    #pragma unroll
    for (int j2=0;j2<8;j2++) acc[i][j2] = 0.f;
  }

  for (int kp = 0; kp < KDIM/96; ++kp){
    __syncthreads();
    for (int idx = tid; idx < 128*24; idx += 256){
      int pp = idx/24, k4 = idx%24;
      size_t prow;
      if (EPI == 1){
        int b = pblk >> 5, tau = pblk & 31;
        int h = ((tau>>2)<<3) + (pp>>4);
        int w = ((tau&3)<<4) + (pp&15);
        prow = (size_t)b*L + h*64 + w;
      } else prow = (size_t)p0 + pp;
      float4 v = *(const float4*)&X[prow*KDIM + (size_t)kp*96 + k4*4];
      xt[pp*24 + (k4 ^ (pp&7))] = v;
    }
    __syncthreads();

    for (int k4 = 0; k4 < 24; ++k4){
      float4 wv[8];
      #pragma unroll
      for (int kk=0;kk<4;kk++){
        const float* wr = &W[(size_t)(kp*96 + k4*4 + kk)*OREAL + oc];
        wv[kk*2]   = *(const float4*)wr;
        wv[kk*2+1] = *(const float4*)(wr+4);
      }
      float4 xv[8];
      #pragma unroll
      for (int i=0;i<8;i++) xv[i] = xt[(pg+16*i)*24 + (k4 ^ sw)];
      #pragma unroll
      for (int kk=0;kk<4;kk++){
        const float4 wa = wv[kk*2], wb = wv[kk*2+1];
        #pragma unroll
        for (int i=0;i<8;i++){
          const float xk = ((const float*)&xv[i])[kk];
          acc[i][0] += xk*wa.x; acc[i][1] += xk*wa.y; acc[i][2] += xk*wa.z; acc[i][3] += xk*wa.w;
          acc[i][4] += xk*wb.x; acc[i][5] += xk*wb.y; acc[i][6] += xk*wb.z; acc[i][7] += xk*wb.w;
        }
      }
    }
  }

  if (EPI == 0){
    #pragma unroll
    for (int i=0;i<8;i++){
      size_t p = (size_t)p0 + pg + 16*i;
      if (oc < Din){
        *(float4*)&out0[p*Din + oc]     = make_float4(acc[i][0],acc[i][1],acc[i][2],acc[i][3]);
        *(float4*)&out0[p*Din + oc + 4] = make_float4(acc[i][4],acc[i][5],acc[i][6],acc[i][7]);
      } else {
        int zo = oc - Din;
        *(float4*)&out1[p*Din + zo]     = make_float4(siluf_(acc[i][0]),siluf_(acc[i][1]),siluf_(acc[i][2]),siluf_(acc[i][3]));
        *(float4*)&out1[p*Din + zo + 4] = make_float4(siluf_(acc[i][4]),siluf_(acc[i][5]),siluf_(acc[i][6]),siluf_(acc[i][7]));
      }
    }
  } else if (EPI == 1){
    const int b = pblk >> 5, tau = pblk & 31;
    #pragma unroll
    for (int i=0;i<8;i++){
      int q = pg + 16*i;
      int h = ((tau>>2)<<3) + (q>>4);
      int w = ((tau&3)<<4) + (q&15);
      int hw = h*64 + w;
      int t1 = ((hw&63)<<6) | (hw>>6);
      #pragma unroll
      for (int j2=0;j2<8;j2++){
        int c = oc + j2;
        int kd = c / CPROJ; int cc = c - kd*CPROJ;
        int t = (kd==0)? hw : (kd==1)? t1 : (kd==2)? (L-1-hw) : (L-1-t1);
        int dcol = (cc < 6) ? (32+cc) : (cc-6);
        out0[((size_t)(b*Kd+kd)*L + t)*ROWW + dcol] = acc[i][j2];
      }
    }
  } else {
    #pragma unroll
    for (int i=0;i<8;i++){
      size_t p = (size_t)p0 + pg + 16*i;
      *(float4*)&out0[p*Dm + oc]     = make_float4(acc[i][0],acc[i][1],acc[i][2],acc[i][3]);
      *(float4*)&out0[p*Dm + oc + 4] = make_float4(acc[i][4],acc[i][5],acc[i][6],acc[i][7]);
    }
  }
}

// ---------------- depthwise 3x3 conv + bias + silu ----------------
__global__ __launch_bounds__(256) void conv_kernel(const float* __restrict__ xp,
    const float* __restrict__ cw, const float* __restrict__ cb, float* __restrict__ u){
  const int gid = blockIdx.x * 256 + threadIdx.x;
  const int d = gid % Din; const int p = gid / Din;
  const int b = p / L; const int hw = p % L; const int h = hw >> 6; const int w = hw & 63;
  float acc = cb[d];
  #pragma unroll
  for (int i=-1;i<=1;i++){
    const int hh = h + i; if (hh < 0 || hh >= Hh) continue;
    #pragma unroll
    for (int j=-1;j<=1;j++){
      const int ww = w + j; if (ww < 0 || ww >= Ww) continue;
      acc += xp[((size_t)(b*L + hh*Ww + ww))*Din + d] * cw[d*9 + (i+1)*3 + (j+1)];
    }
  }
  u[(size_t)p*Din + d] = siluf_(acc);
}

// u position of direction k's timestep t
__device__ __forceinline__ int pos_of(int k, int t){
  if (k == 0) return t;
  if (k == 1) return ((t & 63) << 6) | (t >> 6);
  if (k == 2) return L-1-t;
  const int tp = L-1-t; return ((tp & 63) << 6) | (tp >> 6);
}

// power ladder: e[n] = e1^(n+1), tree-shaped (depth 4)
__device__ __forceinline__ void ladder_(float e1, float* e){
  e[0]=e1;
  #pragma unroll
  for (int n=1;n<16;n++){ int P=n+1; e[n] = e[(P+1)/2 - 1] * e[P/2 - 1]; }
}

// ---------------- scan pass 1: per-chunk local scan -> q (zero-init end state), S (sum delta) ----------------
__global__ __launch_bounds__(192) void scanq_kernel(const float* __restrict__ u,
    const float* __restrict__ xq, const float* __restrict__ dtw,
    const float* __restrict__ dtb, const float* __restrict__ alog,
    float* __restrict__ qout, float* __restrict__ Sout){
  const int bid = blockIdx.x;
  const int c = bid & 63; const int k = (bid >> 6) & 3; const int b = bid >> 8;
  const int d = threadIdx.x;
  const int bk = b*Kd + k;
  float wdt[6];
  #pragma unroll
  for (int r=0;r<6;r++) wdt[r] = dtw[(k*Din + d)*6 + r];
  const float bias = dtb[k*Din + d];
  float a2[16]; bool fastb = true;
  #pragma unroll
  for (int n=0;n<16;n++){
    a2[n] = -__expf(alog[(k*Din + d)*16 + n]);
    fastb = fastb && (fabsf(a2[n] + (float)(n+1)) < 1e-5f*(float)(n+1));
  }
  const bool fast = (bool)__all((int)fastb);
  float hst[16];
  #pragma unroll
  for (int n=0;n<16;n++) hst[n] = 0.f;
  float S = 0.f;
  const int t0 = c * CHUNK;
  for (int t = t0; t < t0 + CHUNK; ++t){
    const float* __restrict__ row = xq + ((size_t)bk*L + t)*ROWW;
    float dr = bias;
    #pragma unroll
    for (int r=0;r<6;r++) dr += row[32+r]*wdt[r];
    const float p = __expf(dr);
    const float delta = (dr > 20.f) ? dr : __logf(1.f + p);
    S += delta;
    const float uval = u[((size_t)b*L + pos_of(k,t))*Din + d];
    const float du = delta * uval;
    float e[16];
    if (fast){
      ladder_(1.f/(1.f + p), e);   // exp(-softplus(dr)) == 1/(1+e^dr)
    } else {
      #pragma unroll
      for (int n=0;n<16;n++) e[n] = __expf(delta * a2[n]);
    }
    #pragma unroll
    for (int n=0;n<16;n++) hst[n] = e[n]*hst[n] + du*row[n];
  }
  const size_t base = ((size_t)bk*NCHUNK + c)*Ns*Din + d;
  #pragma unroll
  for (int n=0;n<16;n++) qout[base + (size_t)n*Din] = hst[n];
  Sout[((size_t)bk*NCHUNK + c)*Din + d] = S;
}

// ---------------- combine: sequential over chunks, h_in written in-place over q ----------------
__global__ __launch_bounds__(256) void combine_kernel(const float* __restrict__ alog,
    float* __restrict__ q, const float* __restrict__ Sin){
  const int gid = blockIdx.x * 256 + threadIdx.x;
  if (gid >= B_SZ*Kd*Ns*Din) return;
  const int d = gid % Din; const int n = (gid / Din) % Ns; const int bk = gid / (Din*Ns);
  const int k = bk & 3;
  const float A = -__expf(alog[(k*Din + d)*16 + n]);
  float h = 0.f;
  for (int c=0;c<NCHUNK;c++){
    const size_t idx = (((size_t)bk*NCHUNK + c)*Ns + n)*Din + d;
    const float qv = q[idx];
    q[idx] = h;
    h = __expf(A * Sin[((size_t)bk*NCHUNK + c)*Din + d]) * h + qv;
  }
}

// ---------------- scan pass 2: one chain per block, no LDS, direct per-direction store ----------------
__global__ __launch_bounds__(192) void scany_kernel(const float* __restrict__ u,
    const float* __restrict__ xq, const float* __restrict__ dtw,
    const float* __restrict__ dtb, const float* __restrict__ alog,
    const float* __restrict__ Dsin, const float* __restrict__ hin,
    float* __restrict__ y0, float* __restrict__ y1,
    float* __restrict__ y2, float* __restrict__ y3){
  const int bid = blockIdx.x;
  const int c = bid & 63; const int k = (bid >> 6) & 3; const int b = bid >> 8;
  const int d = threadIdx.x;
  const int bk = b*Kd + k;
  float* __restrict__ ybuf = (k==0)? y0 : (k==1)? y1 : (k==2)? y2 : y3;

  float wdt[6];
  #pragma unroll
  for (int r=0;r<6;r++) wdt[r] = dtw[(k*Din + d)*6 + r];
  const float bias = dtb[k*Din + d];
  const float Dval = Dsin[k*Din + d];
  float a2[16]; bool fastb = true;
  #pragma unroll
  for (int n=0;n<16;n++){
    a2[n] = -__expf(alog[(k*Din + d)*16 + n]);
    fastb = fastb && (fabsf(a2[n] + (float)(n+1)) < 1e-5f*(float)(n+1));
  }
  const bool fast = (bool)__all((int)fastb);
  float hst[16];
  const size_t hbase = ((size_t)bk*NCHUNK + c)*Ns*Din + d;
  #pragma unroll
  for (int n=0;n<16;n++) hst[n] = hin[hbase + (size_t)n*Din];

  const int t0 = c * CHUNK;
  for (int t = t0; t < t0 + CHUNK; ++t){
    const float* __restrict__ row = xq + ((size_t)bk*L + t)*ROWW;
    float dr = bias;
    #pragma unroll
    for (int r=0;r<6;r++) dr += row[32+r]*wdt[r];
    const float p = __expf(dr);
    const float delta = (dr > 20.f) ? dr : __logf(1.f + p);
    const int gp = pos_of(k,t);
    const float uval = u[((size_t)b*L + gp)*Din + d];
    const float du = delta * uval;
    float e[16];
    if (fast){
      ladder_(1.f/(1.f + p), e);
    } else {
      #pragma unroll
      for (int n=0;n<16;n++) e[n] = __expf(delta * a2[n]);
    }
    float ya=0.f,yb=0.f,yc=0.f,yd=0.f;
    #pragma unroll
    for (int n=0;n<16;n+=4){
      hst[n]   = e[n]*hst[n]     + du*row[n];
      hst[n+1] = e[n+1]*hst[n+1] + du*row[n+1];
      hst[n+2] = e[n+2]*hst[n+2] + du*row[n+2];
      hst[n+3] = e[n+3]*hst[n+3] + du*row[n+3];
      ya += hst[n]*row[16+n];   yb += hst[n+1]*row[17+n];
      yc += hst[n+2]*row[18+n]; yd += hst[n+3]*row[19+n];
    }
    ybuf[((size_t)b*L + gp)*Din + d] = (ya+yb)+(yc+yd) + Dval*uval;
  }
}

// ---------------- merge(4 bufs) + LN + gate ----------------
__global__ __launch_bounds__(192) void lnz_kernel(const float* __restrict__ y0,
    const float* __restrict__ y1, const float* __restrict__ y2, const float* __restrict__ y3,
    const float* __restrict__ z,
    const float* __restrict__ gw, const float* __restrict__ gb,
    float* __restrict__ yg){
  __shared__ float red[2][4];
  const int p = blockIdx.x;
  const int d = threadIdx.x;
  const size_t i = (size_t)p*Din + d;
  const float yv = (y0[i]+y1[i]) + (y2[i]+y3[i]);
  float s = yv, ss = yv*yv;
  #pragma unroll
  for (int off=32; off>=1; off>>=1){ s += __shfl_down(s, off); ss += __shfl_down(ss, off); }
  const int wave = d >> 6;
  if ((d & 63) == 0){ red[0][wave] = s; red[1][wave] = ss; }
  __syncthreads();
  const float mu = (red[0][0]+red[0][1]+red[0][2]) * (1.f/Din);
  const float var = (red[1][0]+red[1][1]+red[1][2]) * (1.f/Din) - mu*mu;
  const float inv = rsqrtf(var + 1e-5f);
  yg[i] = ((yv - mu)*inv*gw[d] + gb[d]) * z[i];
}

extern "C" void kernel_launch(void* const* d_in, const int* in_sizes, int n_in,
                              void* d_out, int out_size, void* d_ws, size_t ws_size,
                              hipStream_t stream) {
  const float* x      = (const float*)d_in[0];
  const float* inw    = (const float*)d_in[1];
  const float* convw  = (const float*)d_in[2];
  const float* convb  = (const float*)d_in[3];
  const float* xprojw = (const float*)d_in[4];
  const float* dtw    = (const float*)d_in[5];
  const float* dtb    = (const float*)d_in[6];
  const float* alog   = (const float*)d_in[7];
  const float* Ds     = (const float*)d_in[8];
  const float* gw     = (const float*)d_in[9];
  const float* gb     = (const float*)d_in[10];
  const float* outw   = (const float*)d_in[11];
  float* out = (float*)d_out;

  float* ws = (float*)d_ws;
  const size_t nBLD  = (size_t)B_SZ*L*Din;
  const size_t nXQ   = (size_t)B_SZ*Kd*L*ROWW;
  const size_t nQ    = (size_t)B_SZ*Kd*NCHUNK*Ns*Din;
  const size_t nS    = (size_t)B_SZ*Kd*NCHUNK*Din;
  size_t off = 0;
  float* xpart = ws + off; off += nBLD;   // reused as ybuf0 after conv
  float* zbuf  = ws + off; off += nBLD;
  float* ubuf  = ws + off; off += nBLD;
  float* xq    = ws + off; off += nXQ;
  float* qbuf  = ws + off; off += nQ;     // h_in in-place; reused as yg after scany
  float* Sbuf  = ws + off; off += nS;
  float* yb1   = ws + off; off += nBLD;
  float* yb2   = ws + off; off += nBLD;
  float* yb3   = ws + off; off += nBLD;
  float* wt_in = ws + off; off += (size_t)Dm*2*Din;
  float* wt_x  = ws + off; off += (size_t)Din*Kd*CPROJ;
  float* wt_out= ws + off; off += (size_t)Din*Dm;

  const int prepN = Dm*2*Din + Din*Kd*CPROJ + Din*Dm;
  prep_kernel<<<(prepN + 255)/256, 256, 0, stream>>>(inw, xprojw, outw, wt_in, wt_x, wt_out);
  gemm_kernel<Dm, 2*Din, 0><<<256*3, 256, 0, stream>>>(x, wt_in, xpart, zbuf);
  conv_kernel<<<(int)(nBLD/256), 256, 0, stream>>>(xpart, convw, convb, ubuf);
  gemm_kernel<Din, Kd*CPROJ, 1><<<256*2, 256, 0, stream>>>(ubuf, wt_x, xq, nullptr);
  scanq_kernel<<<B_SZ*Kd*NCHUNK, Din, 0, stream>>>(ubuf, xq, dtw, dtb, alog, qbuf, Sbuf);
  combine_kernel<<<(B_SZ*Kd*Ns*Din + 255)/256, 256, 0, stream>>>(alog, qbuf, Sbuf);
  scany_kernel<<<B_SZ*Kd*NCHUNK, Din, 0, stream>>>(ubuf, xq, dtw, dtb, alog, Ds, qbuf,
                                                   xpart, yb1, yb2, yb3);
  lnz_kernel<<<B_SZ*L, Din, 0, stream>>>(xpart, yb1, yb2, yb3, zbuf, gw, gb, qbuf);
  gemm_kernel<Din, Dm, 2><<<256*1, 256, 0, stream>>>(qbuf, wt_out, out, nullptr);
}

// Round 5
// 505.801 us; speedup vs baseline: 1.2250x; 1.0371x over previous
//
#include <hip/hip_runtime.h>
#include <math.h>

#define B_SZ 8
#define Hh 64
#define Ww 64
#define L 4096
#define Dm 96
#define Din 192
#define Kd 4
#define Ns 16
#define CPROJ 38
#define ROWW 40           // padded permuted row: [B16|C16|dt6|pad2]
#define NCHUNK 128
#define CHUNK 32

__device__ __forceinline__ float siluf_(float x){ return x / (1.f + __expf(-x)); }

// ---------------- prep: transpose weights ----------------
__global__ void prep_kernel(const float* __restrict__ inw,    // (384,96)
                            const float* __restrict__ xpw,    // (4,38,192)
                            const float* __restrict__ outw,   // (96,192)
                            float* __restrict__ wt_in,        // (96,384)
                            float* __restrict__ wt_x,         // (192,152)
                            float* __restrict__ wt_out){      // (192,96)
  int i = blockIdx.x * blockDim.x + threadIdx.x;
  if (i < Dm*2*Din){ int k = i/(2*Din); int o = i%(2*Din); wt_in[i] = inw[o*Dm + k]; }
  int j = i - Dm*2*Din;
  if (j >= 0 && j < Din*Kd*CPROJ){ int k = j/(Kd*CPROJ); int c = j%(Kd*CPROJ); wt_x[j] = xpw[c*Din + k]; }
  int l = j - Din*Kd*CPROJ;
  if (l >= 0 && l < Din*Dm){ int dd = l/Dm; int o = l%Dm; wt_out[l] = outw[o*Din + dd]; }
}

// ---------------- generic tiled GEMM: C(128p x 128o tile) = X(p,K) @ W(K,O) ----------------
template<int KDIM, int OREAL, int EPI>
__global__ __launch_bounds__(256) void gemm_kernel(const float* __restrict__ X,
    const float* __restrict__ W, float* __restrict__ out0, float* __restrict__ out1){
  __shared__ float4 xt[128*24];    // 48 KB
  const int tid = threadIdx.x;
  const int pg = tid & 15, og = tid >> 4;
  const int pblk = blockIdx.x & 255;
  const int oblk = blockIdx.x >> 8;
  const int p0 = pblk * 128;
  const bool act = (oblk*128 + og*8) < OREAL;   // early-out for padded o-columns
  int oc = oblk*128 + og*8;
  if (oc > OREAL-8) oc = OREAL-8;
  const int sw = pg & 7;

  float acc[8][8];
  #pragma unroll
  for (int i=0;i<8;i++){
    #pragma unroll
    for (int j2=0;j2<8;j2++) acc[i][j2] = 0.f;
  }

  for (int kp = 0; kp < KDIM/96; ++kp){
    __syncthreads();
    for (int idx = tid; idx < 128*24; idx += 256){
      int pp = idx/24, k4 = idx%24;
      size_t prow;
      if (EPI == 1){
        int b = pblk >> 5, tau = pblk & 31;
        int h = ((tau>>2)<<3) + (pp>>4);
        int w = ((tau&3)<<4) + (pp&15);
        prow = (size_t)b*L + h*64 + w;
      } else prow = (size_t)p0 + pp;
      float4 v = *(const float4*)&X[prow*KDIM + (size_t)kp*96 + k4*4];
      xt[pp*24 + (k4 ^ (pp&7))] = v;
    }
    __syncthreads();

    if (act){
      for (int k4 = 0; k4 < 24; ++k4){
        float4 wv[8];
        #pragma unroll
        for (int kk=0;kk<4;kk++){
          const float* wr = &W[(size_t)(kp*96 + k4*4 + kk)*OREAL + oc];
          wv[kk*2]   = *(const float4*)wr;
          wv[kk*2+1] = *(const float4*)(wr+4);
        }
        float4 xv[8];
        #pragma unroll
        for (int i=0;i<8;i++) xv[i] = xt[(pg+16*i)*24 + (k4 ^ sw)];
        #pragma unroll
        for (int kk=0;kk<4;kk++){
          const float4 wa = wv[kk*2], wb = wv[kk*2+1];
          #pragma unroll
          for (int i=0;i<8;i++){
            const float xk = ((const float*)&xv[i])[kk];
            acc[i][0] += xk*wa.x; acc[i][1] += xk*wa.y; acc[i][2] += xk*wa.z; acc[i][3] += xk*wa.w;
            acc[i][4] += xk*wb.x; acc[i][5] += xk*wb.y; acc[i][6] += xk*wb.z; acc[i][7] += xk*wb.w;
          }
        }
      }
    }
  }

  if (!act) return;
  if (EPI == 0){
    #pragma unroll
    for (int i=0;i<8;i++){
      size_t p = (size_t)p0 + pg + 16*i;
      if (oc < Din){
        *(float4*)&out0[p*Din + oc]     = make_float4(acc[i][0],acc[i][1],acc[i][2],acc[i][3]);
        *(float4*)&out0[p*Din + oc + 4] = make_float4(acc[i][4],acc[i][5],acc[i][6],acc[i][7]);
      } else {
        int zo = oc - Din;
        *(float4*)&out1[p*Din + zo]     = make_float4(siluf_(acc[i][0]),siluf_(acc[i][1]),siluf_(acc[i][2]),siluf_(acc[i][3]));
        *(float4*)&out1[p*Din + zo + 4] = make_float4(siluf_(acc[i][4]),siluf_(acc[i][5]),siluf_(acc[i][6]),siluf_(acc[i][7]));
      }
    }
  } else if (EPI == 1){
    const int b = pblk >> 5, tau = pblk & 31;
    #pragma unroll
    for (int i=0;i<8;i++){
      int q = pg + 16*i;
      int h = ((tau>>2)<<3) + (q>>4);
      int w = ((tau&3)<<4) + (q&15);
      int hw = h*64 + w;
      int t1 = ((hw&63)<<6) | (hw>>6);
      #pragma unroll
      for (int j2=0;j2<8;j2++){
        int c = oc + j2;
        int kd = c / CPROJ; int cc = c - kd*CPROJ;
        int t = (kd==0)? hw : (kd==1)? t1 : (kd==2)? (L-1-hw) : (L-1-t1);
        int dcol = (cc < 6) ? (32+cc) : (cc-6);
        out0[((size_t)(b*Kd+kd)*L + t)*ROWW + dcol] = acc[i][j2];
      }
    }
  } else {
    #pragma unroll
    for (int i=0;i<8;i++){
      size_t p = (size_t)p0 + pg + 16*i;
      *(float4*)&out0[p*Dm + oc]     = make_float4(acc[i][0],acc[i][1],acc[i][2],acc[i][3]);
      *(float4*)&out0[p*Dm + oc + 4] = make_float4(acc[i][4],acc[i][5],acc[i][6],acc[i][7]);
    }
  }
}

// ---------------- depthwise 3x3 conv + bias + silu ----------------
__global__ __launch_bounds__(256) void conv_kernel(const float* __restrict__ xp,
    const float* __restrict__ cw, const float* __restrict__ cb, float* __restrict__ u){
  const int gid = blockIdx.x * 256 + threadIdx.x;
  const int d = gid % Din; const int p = gid / Din;
  const int b = p / L; const int hw = p % L; const int h = hw >> 6; const int w = hw & 63;
  float acc = cb[d];
  #pragma unroll
  for (int i=-1;i<=1;i++){
    const int hh = h + i; if (hh < 0 || hh >= Hh) continue;
    #pragma unroll
    for (int j=-1;j<=1;j++){
      const int ww = w + j; if (ww < 0 || ww >= Ww) continue;
      acc += xp[((size_t)(b*L + hh*Ww + ww))*Din + d] * cw[d*9 + (i+1)*3 + (j+1)];
    }
  }
  u[(size_t)p*Din + d] = siluf_(acc);
}

// u position of direction k's timestep t
__device__ __forceinline__ int pos_of(int k, int t){
  if (k == 0) return t;
  if (k == 1) return ((t & 63) << 6) | (t >> 6);
  if (k == 2) return L-1-t;
  const int tp = L-1-t; return ((tp & 63) << 6) | (tp >> 6);
}

// power ladder: e[n] = e1^(n+1), tree-shaped (depth 4)
__device__ __forceinline__ void ladder_(float e1, float* e){
  e[0]=e1;
  #pragma unroll
  for (int n=1;n<16;n++){ int P=n+1; e[n] = e[(P+1)/2 - 1] * e[P/2 - 1]; }
}

// ---------------- scan pass 1: per-chunk local scan -> q (zero-init end state), S (sum delta) ----------------
__global__ __launch_bounds__(192) void scanq_kernel(const float* __restrict__ u,
    const float* __restrict__ xq, const float* __restrict__ dtw,
    const float* __restrict__ dtb, const float* __restrict__ alog,
    float* __restrict__ qout, float* __restrict__ Sout){
  const int bid = blockIdx.x;
  const int c = bid & (NCHUNK-1); const int k = (bid >> 7) & 3; const int b = bid >> 9;
  const int d = threadIdx.x;
  const int bk = b*Kd + k;
  float wdt[6];
  #pragma unroll
  for (int r=0;r<6;r++) wdt[r] = dtw[(k*Din + d)*6 + r];
  const float bias = dtb[k*Din + d];
  float a2[16]; bool fastb = true;
  #pragma unroll
  for (int n=0;n<16;n++){
    a2[n] = -__expf(alog[(k*Din + d)*16 + n]);
    fastb = fastb && (fabsf(a2[n] + (float)(n+1)) < 1e-5f*(float)(n+1));
  }
  const bool fast = (bool)__all((int)fastb);
  float hst[16];
  #pragma unroll
  for (int n=0;n<16;n++) hst[n] = 0.f;
  float S = 0.f;
  const int t0 = c * CHUNK;
  const float* __restrict__ urow = u + (size_t)b*L*Din + d;
  for (int t = t0; t < t0 + CHUNK; ++t){
    const float* __restrict__ row = xq + ((size_t)bk*L + t)*ROWW;
    float dr = bias;
    #pragma unroll
    for (int r=0;r<6;r++) dr += row[32+r]*wdt[r];
    const float p = __expf(dr);
    const float delta = (dr > 20.f) ? dr : __logf(1.f + p);
    S += delta;
    const float uval = urow[(size_t)pos_of(k,t)*Din];
    const float du = delta * uval;
    float e[16];
    if (fast){
      ladder_(1.f/(1.f + p), e);   // exp(-softplus(dr)) == 1/(1+e^dr)
    } else {
      #pragma unroll
      for (int n=0;n<16;n++) e[n] = __expf(delta * a2[n]);
    }
    #pragma unroll
    for (int n=0;n<16;n++) hst[n] = e[n]*hst[n] + du*row[n];
  }
  const size_t base = ((size_t)bk*NCHUNK + c)*Ns*Din + d;
  #pragma unroll
  for (int n=0;n<16;n++) qout[base + (size_t)n*Din] = hst[n];
  Sout[((size_t)bk*NCHUNK + c)*Din + d] = S;
}

// ---------------- combine: sequential over chunks, h_in written in-place over q ----------------
__global__ __launch_bounds__(256) void combine_kernel(const float* __restrict__ alog,
    float* __restrict__ q, const float* __restrict__ Sin){
  const int gid = blockIdx.x * 256 + threadIdx.x;
  if (gid >= B_SZ*Kd*Ns*Din) return;
  const int d = gid % Din; const int n = (gid / Din) % Ns; const int bk = gid / (Din*Ns);
  const int k = bk & 3;
  const float A = -__expf(alog[(k*Din + d)*16 + n]);
  float h = 0.f;
  for (int c=0;c<NCHUNK;c++){
    const size_t idx = (((size_t)bk*NCHUNK + c)*Ns + n)*Din + d;
    const float qv = q[idx];
    q[idx] = h;
    h = __expf(A * Sin[((size_t)bk*NCHUNK + c)*Din + d]) * h + qv;
  }
}

// ---------------- scan pass 2: one chain per block, atomic merge into ym ----------------
__global__ __launch_bounds__(192) void scany_kernel(const float* __restrict__ u,
    const float* __restrict__ xq, const float* __restrict__ dtw,
    const float* __restrict__ dtb, const float* __restrict__ alog,
    const float* __restrict__ Dsin, const float* __restrict__ hin,
    float* __restrict__ ym){
  const int bid = blockIdx.x;
  const int c = bid & (NCHUNK-1); const int k = (bid >> 7) & 3; const int b = bid >> 9;
  const int d = threadIdx.x;
  const int bk = b*Kd + k;

  float wdt[6];
  #pragma unroll
  for (int r=0;r<6;r++) wdt[r] = dtw[(k*Din + d)*6 + r];
  const float bias = dtb[k*Din + d];
  const float Dval = Dsin[k*Din + d];
  float a2[16]; bool fastb = true;
  #pragma unroll
  for (int n=0;n<16;n++){
    a2[n] = -__expf(alog[(k*Din + d)*16 + n]);
    fastb = fastb && (fabsf(a2[n] + (float)(n+1)) < 1e-5f*(float)(n+1));
  }
  const bool fast = (bool)__all((int)fastb);
  float hst[16];
  const size_t hbase = ((size_t)bk*NCHUNK + c)*Ns*Din + d;
  #pragma unroll
  for (int n=0;n<16;n++) hst[n] = hin[hbase + (size_t)n*Din];

  const int t0 = c * CHUNK;
  const float* __restrict__ urow = u + (size_t)b*L*Din + d;
  float* __restrict__ yrow = ym + (size_t)b*L*Din + d;
  for (int t = t0; t < t0 + CHUNK; ++t){
    const float* __restrict__ row = xq + ((size_t)bk*L + t)*ROWW;
    float dr = bias;
    #pragma unroll
    for (int r=0;r<6;r++) dr += row[32+r]*wdt[r];
    const float p = __expf(dr);
    const float delta = (dr > 20.f) ? dr : __logf(1.f + p);
    const int gp = pos_of(k,t);
    const float uval = urow[(size_t)gp*Din];
    const float du = delta * uval;
    float e[16];
    if (fast){
      ladder_(1.f/(1.f + p), e);
    } else {
      #pragma unroll
      for (int n=0;n<16;n++) e[n] = __expf(delta * a2[n]);
    }
    float ya=0.f,yb=0.f,yc=0.f,yd=0.f;
    #pragma unroll
    for (int n=0;n<16;n+=4){
      hst[n]   = e[n]*hst[n]     + du*row[n];
      hst[n+1] = e[n+1]*hst[n+1] + du*row[n+1];
      hst[n+2] = e[n+2]*hst[n+2] + du*row[n+2];
      hst[n+3] = e[n+3]*hst[n+3] + du*row[n+3];
      ya += hst[n]*row[16+n];   yb += hst[n+1]*row[17+n];
      yc += hst[n+2]*row[18+n]; yd += hst[n+3]*row[19+n];
    }
    atomicAdd(&yrow[(size_t)gp*Din], (ya+yb)+(yc+yd) + Dval*uval);
  }
}

// ---------------- LN + gate (ym already merged) ----------------
__global__ __launch_bounds__(192) void lnz_kernel(const float* __restrict__ ym,
    const float* __restrict__ z,
    const float* __restrict__ gw, const float* __restrict__ gb,
    float* __restrict__ yg){
  __shared__ float red[2][4];
  const int p = blockIdx.x;
  const int d = threadIdx.x;
  const size_t i = (size_t)p*Din + d;
  const float yv = ym[i];
  float s = yv, ss = yv*yv;
  #pragma unroll
  for (int off=32; off>=1; off>>=1){ s += __shfl_down(s, off); ss += __shfl_down(ss, off); }
  const int wave = d >> 6;
  if ((d & 63) == 0){ red[0][wave] = s; red[1][wave] = ss; }
  __syncthreads();
  const float mu = (red[0][0]+red[0][1]+red[0][2]) * (1.f/Din);
  const float var = (red[1][0]+red[1][1]+red[1][2]) * (1.f/Din) - mu*mu;
  const float inv = rsqrtf(var + 1e-5f);
  yg[i] = ((yv - mu)*inv*gw[d] + gb[d]) * z[i];
}

extern "C" void kernel_launch(void* const* d_in, const int* in_sizes, int n_in,
                              void* d_out, int out_size, void* d_ws, size_t ws_size,
                              hipStream_t stream) {
  const float* x      = (const float*)d_in[0];
  const float* inw    = (const float*)d_in[1];
  const float* convw  = (const float*)d_in[2];
  const float* convb  = (const float*)d_in[3];
  const float* xprojw = (const float*)d_in[4];
  const float* dtw    = (const float*)d_in[5];
  const float* dtb    = (const float*)d_in[6];
  const float* alog   = (const float*)d_in[7];
  const float* Ds     = (const float*)d_in[8];
  const float* gw     = (const float*)d_in[9];
  const float* gb     = (const float*)d_in[10];
  const float* outw   = (const float*)d_in[11];
  float* out = (float*)d_out;

  float* ws = (float*)d_ws;
  const size_t nBLD  = (size_t)B_SZ*L*Din;
  const size_t nXQ   = (size_t)B_SZ*Kd*L*ROWW;
  const size_t nQ    = (size_t)B_SZ*Kd*NCHUNK*Ns*Din;
  const size_t nS    = (size_t)B_SZ*Kd*NCHUNK*Din;
  size_t off = 0;
  float* xpart = ws + off; off += nBLD;
  float* zbuf  = ws + off; off += nBLD;
  float* ubuf  = ws + off; off += nBLD;
  float* xq    = ws + off; off += nXQ;
  float* qbuf  = ws + off; off += nQ;     // h_in in-place; reused as yg after scany
  float* Sbuf  = ws + off; off += nS;
  float* ym    = ws + off; off += nBLD;
  float* wt_in = ws + off; off += (size_t)Dm*2*Din;
  float* wt_x  = ws + off; off += (size_t)Din*Kd*CPROJ;
  float* wt_out= ws + off; off += (size_t)Din*Dm;

  hipMemsetAsync(ym, 0, nBLD*sizeof(float), stream);

  const int prepN = Dm*2*Din + Din*Kd*CPROJ + Din*Dm;
  prep_kernel<<<(prepN + 255)/256, 256, 0, stream>>>(inw, xprojw, outw, wt_in, wt_x, wt_out);
  gemm_kernel<Dm, 2*Din, 0><<<256*3, 256, 0, stream>>>(x, wt_in, xpart, zbuf);
  conv_kernel<<<(int)(nBLD/256), 256, 0, stream>>>(xpart, convw, convb, ubuf);
  gemm_kernel<Din, Kd*CPROJ, 1><<<256*2, 256, 0, stream>>>(ubuf, wt_x, xq, nullptr);
  scanq_kernel<<<B_SZ*Kd*NCHUNK, Din, 0, stream>>>(ubuf, xq, dtw, dtb, alog, qbuf, Sbuf);
  combine_kernel<<<(B_SZ*Kd*Ns*Din + 255)/256, 256, 0, stream>>>(alog, qbuf, Sbuf);
  scany_kernel<<<B_SZ*Kd*NCHUNK, Din, 0, stream>>>(ubuf, xq, dtw, dtb, alog, Ds, qbuf, ym);
  lnz_kernel<<<B_SZ*L, Din, 0, stream>>>(ym, zbuf, gw, gb, qbuf);
  gemm_kernel<Din, Dm, 2><<<256*1, 256, 0, stream>>>(qbuf, wt_out, out, nullptr);
}